// Round 5
// baseline (188.509 us; speedup 1.0000x reference)
//
#include <hip/hip_runtime.h>
#include <stdint.h>

typedef __bf16 bf16x8 __attribute__((ext_vector_type(8)));
typedef float  f32x4  __attribute__((ext_vector_type(4)));

#define ATTN_SCALE 2.7621359e-3f   // 1/(sqrt(128)*sqrt(1024))

__device__ __forceinline__ unsigned short f2bf(float f) {
  union { float f; uint32_t u; } v; v.f = f;
  uint32_t u = v.u;
  uint32_t r = (u + 0x7FFFu + ((u >> 16) & 1u)) >> 16;   // RNE
  return (unsigned short)r;
}

__device__ __forceinline__ void load_lds16(const unsigned short* g, unsigned short* l) {
  __builtin_amdgcn_global_load_lds(
      (const __attribute__((address_space(1))) void*)g,
      (__attribute__((address_space(3))) void*)l, 16, 0, 0);
}

__device__ __forceinline__ f32x4 mfma16(bf16x8 a, bf16x8 b, f32x4 c) {
  return __builtin_amdgcn_mfma_f32_16x16x32_bf16(a, b, c, 0, 0, 0);
}

__device__ __forceinline__ bf16x8 ones_bf16() {
  union { unsigned short u[8]; bf16x8 v; } c;
#pragma unroll
  for (int j = 0; j < 8; ++j) c.u[j] = 0x3F80;   // bf16 1.0
  return c.v;
}

// ---------------------------------------------------------------- convert x
__global__ __launch_bounds__(256) void k_cvt(const float* __restrict__ src,
                                             unsigned short* __restrict__ dst, int n4) {
  int i = blockIdx.x * 256 + threadIdx.x;
  if (i >= n4) return;
  float4 f = ((const float4*)src)[i];
  ushort4 o;
  o.x = f2bf(f.x); o.y = f2bf(f.y); o.z = f2bf(f.z); o.w = f2bf(f.w);
  ((ushort4*)dst)[i] = o;
}

// ---------------------------------------------------------------- convert 3 weights
__global__ __launch_bounds__(256) void k_cvtw(const float* __restrict__ a,
                                              const float* __restrict__ b,
                                              const float* __restrict__ c,
                                              unsigned short* __restrict__ dst) {
  int i = blockIdx.x * 256 + threadIdx.x;      // 0..98303 float4 groups
  int sel = i >> 15, off = i & 32767;
  const float* s = (sel == 0) ? a : (sel == 1) ? b : c;
  float4 f = ((const float4*)s)[off];
  ushort4 o;
  o.x = f2bf(f.x); o.y = f2bf(f.y); o.z = f2bf(f.z); o.w = f2bf(f.w);
  ((ushort4*)dst)[i] = o;
}

// ---------------------------------------------------------------- QKV projection GEMM
__global__ __launch_bounds__(256, 2) void k_proj(
    const unsigned short* __restrict__ X,    // [16384][1024] bf16
    const unsigned short* __restrict__ W,    // [3][128][1024] bf16
    unsigned short* __restrict__ Qb,         // [16384][128]
    unsigned short* __restrict__ Kb,         // [16384][128]
    unsigned short* __restrict__ Vt)         // [4][128][4096]
{
  __shared__ __align__(16) unsigned short sm[128 * 32 * 2];   // As | Bs, 16 KB
  unsigned short* As = sm;
  unsigned short* Bs = sm + 4096;
  const int t = threadIdx.x;
  const int mtile = blockIdx.x;          // 0..127
  const int nt = blockIdx.y;             // 0..2
  const int w = t >> 6, lane = t & 63, quad = lane >> 4, l15 = lane & 15;
  const int wm = w & 1, wn = w >> 1;

  const unsigned short* Wsel = W + nt * (128 * 1024);
  const unsigned short* Ag = X + (size_t)(mtile * 128) * 1024;

  const unsigned short* ag0 = Ag + (size_t)(t >> 2) * 1024 + (t & 3) * 8;
  const unsigned short* bg0 = Wsel + (size_t)(t >> 2) * 1024 + (t & 3) * 8;
  unsigned short* aw = &As[(t >> 6) * 512];
  unsigned short* bw = &Bs[(t >> 6) * 512];

  f32x4 acc[4][4] = {};

  for (int kt = 0; kt < 32; ++kt) {
    __syncthreads();
    const unsigned short* ak = ag0 + kt * 32;
    const unsigned short* bk = bg0 + kt * 32;
    load_lds16(ak,             aw);
    load_lds16(ak + 64 * 1024, aw + 2048);
    load_lds16(bk,             bw);
    load_lds16(bk + 64 * 1024, bw + 2048);
    __syncthreads();

    bf16x8 af[4], bfr[4];
#pragma unroll
    for (int i = 0; i < 4; ++i)
      af[i] = *(const bf16x8*)&As[(wm * 64 + i * 16 + l15) * 32 + quad * 8];
#pragma unroll
    for (int j = 0; j < 4; ++j)
      bfr[j] = *(const bf16x8*)&Bs[(wn * 64 + j * 16 + l15) * 32 + quad * 8];
#pragma unroll
    for (int i = 0; i < 4; ++i)
#pragma unroll
      for (int j = 0; j < 4; ++j)
        acc[i][j] = mfma16(af[i], bfr[j], acc[i][j]);
  }

  if (nt != 2) {
    const int m0 = mtile * 128 + wm * 64;
#pragma unroll
    for (int i = 0; i < 4; ++i)
#pragma unroll
      for (int j = 0; j < 4; ++j)
#pragma unroll
        for (int r = 0; r < 4; ++r) {
          int m = m0 + i * 16 + quad * 4 + r;
          int n = wn * 64 + j * 16 + l15;
          float v = acc[i][j][r];
          if (nt == 0) Qb[(size_t)m * 128 + n] = f2bf(v * ATTN_SCALE);
          else         Kb[(size_t)m * 128 + n] = f2bf(v);
        }
  } else {
    // transpose through LDS -> coalesced Vt writes
    // NOTE: jj loop MUST be fully unrolled (j indexes the acc register array;
    // runtime index demotes acc to scratch -> 600 MB spill traffic, round-2).
    float* Ts = (float*)sm;                   // [128 m][17] f32 (8704 B)
    const int bb = mtile >> 5;
    const int s0 = (mtile & 31) * 128;
#pragma unroll
    for (int jj = 0; jj < 8; ++jj) {
      __syncthreads();
      if (wn == (jj >> 2)) {
        const int j = jj & 3;
#pragma unroll
        for (int i = 0; i < 4; ++i)
#pragma unroll
          for (int r = 0; r < 4; ++r)
            Ts[(wm * 64 + i * 16 + quad * 4 + r) * 17 + l15] = acc[i][j][r];
      }
      __syncthreads();
      int n2 = jj * 16 + (t >> 4), m2 = (t & 15) * 8;
      union { unsigned short u[8]; uint4 v; } pk;
#pragma unroll
      for (int e = 0; e < 8; ++e) pk.u[e] = f2bf(Ts[(m2 + e) * 17 + (t >> 4)]);
      *(uint4*)&Vt[((size_t)(bb * 128 + n2)) * 4096 + s0 + m2] = pk.v;
    }
  }
}

// ---------------------------------------------------------------- flash attention
// grid (64 qtiles, 4 batch, 4 key-split), 256 thr.
// Wave w: h=w&1 -> Q rows h*32..; p=w>>1 -> 32-key half of the 64-key tile.
// No online max (scores ~N(0,0.01^2); exp unnormalized is safe; shift cancels).
// Row-sum l via MFMA against ones. K and V single-buffered; per-iter:
//   B1 sync -> issue K,V global_load_lds -> vmcnt(4)+barrier (K resident,
//   V in flight; vmcnt is in-order so (4) waits exactly the 4 K loads) ->
//   QK -> softmax/P -> vmcnt(0)+lgkmcnt(0)+barrier -> PV.
// 40960 B LDS + <=170 regs/wave (launch_bounds 256,3) -> 3 blocks/CU; the
// in-iter K latency is hidden by cross-block TLP (12 waves/CU).
__global__ __launch_bounds__(256, 3) void k_flash(
    const unsigned short* __restrict__ Qb,   // [4][4096][128] bf16, pre-scaled
    const unsigned short* __restrict__ Kb,   // [4][4096][128] bf16
    const unsigned short* __restrict__ Vt,   // [4][128][4096] bf16
    float* __restrict__ Om,                  // [4][16384][128] f32 partials
    float* __restrict__ lp)                  // [4][16384] row sums
{
  __shared__ __align__(16) unsigned short smem[20480];  // 40960 B
  // Ksh = smem[0..8192)   : [64 keys][128 d], chunk-swizzled
  unsigned short* Vsh = smem + 8192;     // [128 d][64 keys], chunk-swizzled
  unsigned short* Psh = smem + 16384;    // per-wave [32 q][stride 32]
  float* Ob  = (float*)smem;             // epilogue overlay [64][128] f32
  float* lsh = (float*)(smem + 16384);   // epilogue overlay [64] f32

  const int t = threadIdx.x;
  const int w = t >> 6, lane = t & 63, quad = lane >> 4, l15 = lane & 15;
  const int h = w & 1, p = w >> 1;
  const int qt = blockIdx.x, b = blockIdx.y, sp = blockIdx.z;

  const unsigned short* Qg = Qb + (size_t)(b * 4096 + qt * 64 + h * 32) * 128;
  const unsigned short* Kg = Kb + (size_t)b * 4096 * 128;
  const unsigned short* Vg = Vt + (size_t)b * 128 * 4096;

  bf16x8 qf[2][4];
#pragma unroll
  for (int mt = 0; mt < 2; ++mt)
#pragma unroll
    for (int kk = 0; kk < 4; ++kk)
      qf[mt][kk] = *(const bf16x8*)&Qg[(size_t)(mt * 16 + l15) * 128 + kk * 32 + quad * 8];

  f32x4 O[2][8] = {};
  f32x4 Ol[2] = {};

  // staging maps (chunk-XOR swizzled on the fetch side):
  // K rows consumed as row = 2*l15+ntk -> swizzle key (row>>1)&7 = (t>>5)&7.
  const unsigned short* kg0 = Kg + (size_t)(t >> 4) * 128 + (((t & 15) ^ ((t >> 5) & 7)) * 8);
  const unsigned short* vg0 = Vg + (size_t)(t >> 3) * 4096 + (((t & 7) ^ ((t >> 3) & 7)) * 8);
  unsigned short* kw = &smem[w * 512];
  unsigned short* vw = &Vsh[w * 512];

  const int kt0 = sp * 16;

  for (int i = 0; i < 16; ++i) {
    __syncthreads();   // B1: prev PV reads done; nothing outstanding on vm
    {
      const unsigned short* kg = kg0 + (size_t)(kt0 + i) * 8192;
#pragma unroll
      for (int it = 0; it < 4; ++it)           // K first (oldest 4 in vmcnt)
        load_lds16(kg + it * 2048, kw + it * 2048);
      const unsigned short* vg = vg0 + (size_t)(kt0 + i) * 64;
#pragma unroll
      for (int it = 0; it < 4; ++it)
        load_lds16(vg + (size_t)it * 131072, vw + it * 2048);
    }
    asm volatile("s_waitcnt vmcnt(4)" ::: "memory");   // K landed
    asm volatile("s_barrier" ::: "memory");            // B2: K visible

    // S = Q K^T on this wave's 32 keys (keys paired even/odd: 2*l15+ntk)
    f32x4 sc[2][2] = {};
#pragma unroll
    for (int ntk = 0; ntk < 2; ++ntk) {
      const int row = p * 32 + 2 * l15 + ntk;
#pragma unroll
      for (int kk = 0; kk < 4; ++kk) {
        bf16x8 kf = *(const bf16x8*)&smem[row * 128 + (((kk * 4 + quad) ^ (l15 & 7)) * 8)];
        sc[0][ntk] = mfma16(qf[0][kk], kf, sc[0][ntk]);
        sc[1][ntk] = mfma16(qf[1][kk], kf, sc[1][ntk]);
      }
    }

    // P = exp(S) (no max shift), packed pair writes (keys 2*l15, 2*l15+1)
#pragma unroll
    for (int mt = 0; mt < 2; ++mt)
#pragma unroll
      for (int r = 0; r < 4; ++r) {
        float e0 = __expf(sc[mt][0][r]);
        float e1 = __expf(sc[mt][1][r]);
        int row = mt * 16 + quad * 4 + r;
        uint32_t pkv = (uint32_t)f2bf(e0) | ((uint32_t)f2bf(e1) << 16);
        *(uint32_t*)&Psh[w * 1024 + row * 32 + 2 * l15] = pkv;
      }

    asm volatile("s_waitcnt vmcnt(0) lgkmcnt(0)" ::: "memory");  // V + P ready
    asm volatile("s_barrier" ::: "memory");                      // B3

    bf16x8 pf0 = *(const bf16x8*)&Psh[w * 1024 + l15 * 32 + quad * 8];
    bf16x8 pf1 = *(const bf16x8*)&Psh[w * 1024 + (16 + l15) * 32 + quad * 8];
    const bf16x8 one = ones_bf16();
    Ol[0] = mfma16(pf0, one, Ol[0]);     // row-sums of P
    Ol[1] = mfma16(pf1, one, Ol[1]);
#pragma unroll
    for (int dt = 0; dt < 8; ++dt) {
      bf16x8 vf = *(const bf16x8*)&Vsh[(dt * 16 + l15) * 64 + (((p * 4 + quad) ^ (l15 & 7)) * 8)];
      O[0][dt] = mfma16(pf0, vf, O[0][dt]);
      O[1][dt] = mfma16(pf1, vf, O[1][dt]);
    }
  }

  // ---- merge the two key-half partials (additive: no max state) ----
  __syncthreads();
  if (p == 1) {
#pragma unroll
    for (int mt = 0; mt < 2; ++mt)
#pragma unroll
      for (int r = 0; r < 4; ++r) {
        int row = h * 32 + mt * 16 + quad * 4 + r;
        if (l15 == 0) lsh[row] = Ol[mt][r];
#pragma unroll
        for (int dt = 0; dt < 8; ++dt)
          Ob[row * 128 + dt * 16 + l15] = O[mt][dt][r];
      }
  }
  __syncthreads();
  if (p == 0) {
    const size_t rowbase = (size_t)b * 4096 + qt * 64;
    float* Omp = Om + (size_t)sp * 2097152;
#pragma unroll
    for (int mt = 0; mt < 2; ++mt)
#pragma unroll
      for (int r = 0; r < 4; ++r) {
        int row = h * 32 + mt * 16 + quad * 4 + r;
#pragma unroll
        for (int dt = 0; dt < 8; ++dt)
          Omp[(rowbase + row) * 128 + dt * 16 + l15] =
              O[mt][dt][r] + Ob[row * 128 + dt * 16 + l15];
        if (l15 == 0)
          lp[(size_t)sp * 16384 + rowbase + row] = Ol[mt][r] + lsh[row];
      }
  }
}

// ---------------------------------------------------------------- merge key-splits
__global__ __launch_bounds__(256) void k_merge(const float* __restrict__ Om,
                                               const float* __restrict__ lp,
                                               float* __restrict__ out) {
  int i = blockIdx.x * 256 + threadIdx.x;   // float4 index, 524288 total
  int row = i >> 5;
  float inv = 1.0f / (lp[row] + lp[16384 + row] + lp[32768 + row] + lp[49152 + row]);
  float4 a = ((const float4*)Om)[i];
  float4 c = ((const float4*)Om)[524288 + i];
  float4 d = ((const float4*)Om)[1048576 + i];
  float4 e = ((const float4*)Om)[1572864 + i];
  float4 o;
  o.x = (a.x + c.x + d.x + e.x) * inv;
  o.y = (a.y + c.y + d.y + e.y) * inv;
  o.z = (a.z + c.z + d.z + e.z) * inv;
  o.w = (a.w + c.w + d.w + e.w) * inv;
  ((float4*)out)[i] = o;
}

// ---------------------------------------------------------------- launch
extern "C" void kernel_launch(void* const* d_in, const int* in_sizes, int n_in,
                              void* d_out, int out_size, void* d_ws, size_t ws_size,
                              hipStream_t stream) {
  const float* x  = (const float*)d_in[0];   // [4,4096,1024]
  const float* Wq = (const float*)d_in[1];   // [128,1024]
  const float* Wk = (const float*)d_in[2];
  const float* Wv = (const float*)d_in[3];
  float* out = (float*)d_out;                // [4,4096,128]

  unsigned short* ws  = (unsigned short*)d_ws;
  unsigned short* xbf = ws;                   // 16,777,216 ush (reused as Om)
  unsigned short* wbf = xbf + 16777216;       // 3*131072
  unsigned short* Qb  = wbf + 393216;         // 2,097,152
  unsigned short* Kb  = Qb + 2097152;
  unsigned short* Vt  = Kb + 2097152;         // 2,097,152
  float* lp  = (float*)(Vt + 2097152);        // 4*16384 f32
  float* Om  = (float*)xbf;                   // 4*16384*128 f32 (overlays xbf)

  k_cvt<<<16384, 256, 0, stream>>>(x, xbf, 4194304);
  k_cvtw<<<384, 256, 0, stream>>>(Wq, Wk, Wv, wbf);
  k_proj<<<dim3(128, 3), 256, 0, stream>>>(xbf, wbf, Qb, Kb, Vt);
  k_flash<<<dim3(64, 4, 4), 256, 0, stream>>>(Qb, Kb, Vt, Om, lp);
  k_merge<<<2048, 256, 0, stream>>>(Om, lp, out);
}

// Round 6
// 181.298 us; speedup vs baseline: 1.0398x; 1.0398x over previous
//
#include <hip/hip_runtime.h>
#include <stdint.h>

typedef __bf16 bf16x8 __attribute__((ext_vector_type(8)));
typedef float  f32x4  __attribute__((ext_vector_type(4)));

#define ATTN_SCALE 2.7621359e-3f   // 1/(sqrt(128)*sqrt(1024))

__device__ __forceinline__ unsigned short f2bf(float f) {
  union { float f; uint32_t u; } v; v.f = f;
  uint32_t u = v.u;
  uint32_t r = (u + 0x7FFFu + ((u >> 16) & 1u)) >> 16;   // RNE
  return (unsigned short)r;
}

__device__ __forceinline__ void load_lds16(const unsigned short* g, unsigned short* l) {
  __builtin_amdgcn_global_load_lds(
      (const __attribute__((address_space(1))) void*)g,
      (__attribute__((address_space(3))) void*)l, 16, 0, 0);
}

__device__ __forceinline__ f32x4 mfma16(bf16x8 a, bf16x8 b, f32x4 c) {
  return __builtin_amdgcn_mfma_f32_16x16x32_bf16(a, b, c, 0, 0, 0);
}

__device__ __forceinline__ bf16x8 ones_bf16() {
  union { unsigned short u[8]; bf16x8 v; } c;
#pragma unroll
  for (int j = 0; j < 8; ++j) c.u[j] = 0x3F80;   // bf16 1.0
  return c.v;
}

// ---------------------------------------------------------------- QKV projection GEMM
// Fused f32->bf16: stages X and W from f32 via register loads (one-iteration
// prefetch), converts, writes bf16 tiles to LDS. lgkm-only barriers keep the
// f32 prefetch loads in flight across the MFMA phase.
__global__ __launch_bounds__(256, 2) void k_proj(
    const float* __restrict__ Xf,    // [16384][1024] f32
    const float* __restrict__ Wqf,   // [128][1024] f32
    const float* __restrict__ Wkf,
    const float* __restrict__ Wvf,
    unsigned short* __restrict__ Qb, // [16384][128] bf16
    unsigned short* __restrict__ Kb, // [16384][128] bf16
    unsigned short* __restrict__ Vt) // [4][128][4096] bf16
{
  __shared__ __align__(16) unsigned short sm[128 * 32 * 2];   // As | Bs, 16 KB
  unsigned short* As = sm;
  unsigned short* Bs = sm + 4096;
  const int t = threadIdx.x;
  const int mtile = blockIdx.x;          // 0..127
  const int nt = blockIdx.y;             // 0..2
  const int w = t >> 6, lane = t & 63, quad = lane >> 4, l15 = lane & 15;
  const int wm = w & 1, wn = w >> 1;

  const float* Wsel = (nt == 0) ? Wqf : (nt == 1) ? Wkf : Wvf;
  const int srow = t >> 1;               // 0..127
  const int scol = (t & 1) * 16;         // 0 or 16
  const float* ax = Xf + ((size_t)(mtile * 128 + srow)) * 1024 + scol;
  const float* bx = Wsel + (size_t)srow * 1024 + scol;
  unsigned short* adst = &As[srow * 32 + scol];
  unsigned short* bdst = &Bs[srow * 32 + scol];

  f32x4 acc[4][4] = {};

  // prologue: load kt=0 into regs
  float4 ar[4], br[4];
#pragma unroll
  for (int j = 0; j < 4; ++j) {
    ar[j] = *(const float4*)(ax + 4 * j);
    br[j] = *(const float4*)(bx + 4 * j);
  }

  for (int kt = 0; kt < 32; ++kt) {
    // convert + write current tile (auto vmcnt waits on ar/br)
    union { unsigned short u[16]; uint4 v[2]; } pa, pb;
#pragma unroll
    for (int j = 0; j < 4; ++j) {
      pa.u[4 * j]     = f2bf(ar[j].x); pa.u[4 * j + 1] = f2bf(ar[j].y);
      pa.u[4 * j + 2] = f2bf(ar[j].z); pa.u[4 * j + 3] = f2bf(ar[j].w);
      pb.u[4 * j]     = f2bf(br[j].x); pb.u[4 * j + 1] = f2bf(br[j].y);
      pb.u[4 * j + 2] = f2bf(br[j].z); pb.u[4 * j + 3] = f2bf(br[j].w);
    }
    *(uint4*)adst = pa.v[0]; *(uint4*)(adst + 8) = pa.v[1];
    *(uint4*)bdst = pb.v[0]; *(uint4*)(bdst + 8) = pb.v[1];

    // issue next-tile f32 loads (in flight across the whole MFMA phase)
    const int ktn = (kt < 31) ? kt + 1 : 31;
#pragma unroll
    for (int j = 0; j < 4; ++j) {
      ar[j] = *(const float4*)(ax + ktn * 32 + 4 * j);
      br[j] = *(const float4*)(bx + ktn * 32 + 4 * j);
    }

    asm volatile("s_waitcnt lgkmcnt(0)" ::: "memory");  // LDS writes visible
    asm volatile("s_barrier" ::: "memory");

    bf16x8 af[4], bfr[4];
#pragma unroll
    for (int i = 0; i < 4; ++i)
      af[i] = *(const bf16x8*)&As[(wm * 64 + i * 16 + l15) * 32 + quad * 8];
#pragma unroll
    for (int j = 0; j < 4; ++j)
      bfr[j] = *(const bf16x8*)&Bs[(wn * 64 + j * 16 + l15) * 32 + quad * 8];
#pragma unroll
    for (int i = 0; i < 4; ++i)
#pragma unroll
      for (int j = 0; j < 4; ++j)
        acc[i][j] = mfma16(af[i], bfr[j], acc[i][j]);

    asm volatile("s_barrier" ::: "memory");  // readers done before next write
  }

  if (nt != 2) {
    const int m0 = mtile * 128 + wm * 64;
#pragma unroll
    for (int i = 0; i < 4; ++i)
#pragma unroll
      for (int j = 0; j < 4; ++j)
#pragma unroll
        for (int r = 0; r < 4; ++r) {
          int m = m0 + i * 16 + quad * 4 + r;
          int n = wn * 64 + j * 16 + l15;
          float v = acc[i][j][r];
          if (nt == 0) Qb[(size_t)m * 128 + n] = f2bf(v * ATTN_SCALE);
          else         Kb[(size_t)m * 128 + n] = f2bf(v);
        }
  } else {
    // transpose through LDS -> coalesced Vt writes
    // NOTE: jj loop MUST be fully unrolled (j indexes the acc register array;
    // runtime index demotes acc to scratch -> 600 MB spill traffic, round-2).
    float* Ts = (float*)sm;                   // [128 m][17] f32 (8704 B)
    const int bb = mtile >> 5;
    const int s0 = (mtile & 31) * 128;
#pragma unroll
    for (int jj = 0; jj < 8; ++jj) {
      __syncthreads();
      if (wn == (jj >> 2)) {
        const int j = jj & 3;
#pragma unroll
        for (int i = 0; i < 4; ++i)
#pragma unroll
          for (int r = 0; r < 4; ++r)
            Ts[(wm * 64 + i * 16 + quad * 4 + r) * 17 + l15] = acc[i][j][r];
      }
      __syncthreads();
      int n2 = jj * 16 + (t >> 4), m2 = (t & 15) * 8;
      union { unsigned short u[8]; uint4 v; } pk;
#pragma unroll
      for (int e = 0; e < 8; ++e) pk.u[e] = f2bf(Ts[(m2 + e) * 17 + (t >> 4)]);
      *(uint4*)&Vt[((size_t)(bb * 128 + n2)) * 4096 + s0 + m2] = pk.v;
    }
  }
}

// ---------------------------------------------------------------- flash attention (full dbuf, dynamic LDS)
// grid (64 qtiles, 4 batch, 2 key-split), 256 thr.
// K AND V double-buffered (75776 B dynamic LDS, >64K static cap): tile i+1 is
// staged during iter i, so the single top-of-iter __syncthreads (whose
// compiler-emitted vmcnt(0) drains one-iteration-old DMA) is the ONLY barrier
// per iteration. P is wave-private (lgkm-only wait). No online max (scores
// ~N(0,0.01^2)); row-sum l via MFMA against ones.
__global__ __launch_bounds__(256, 2) void k_flash_db(
    const unsigned short* __restrict__ Qb,   // [4][4096][128] bf16, pre-scaled
    const unsigned short* __restrict__ Kb,   // [4][4096][128] bf16
    const unsigned short* __restrict__ Vt,   // [4][128][4096] bf16
    float* __restrict__ Om,                  // [2][16384][128] f32 partials
    float* __restrict__ lp)                  // [2][16384] row sums
{
  extern __shared__ __align__(16) unsigned short sm[];  // 75776 B
  // KB: [2][64 keys][128 d] at 0 ; VB: [2][128 d][64 keys] at 16384 ;
  // Psh: 4 waves x [32 q][stride 40] at 32768
  unsigned short* Psh = sm + 32768;
  float* Ob  = (float*)sm;               // epilogue overlay [64][128] f32
  float* lsh = (float*)(sm + 32768);     // epilogue overlay [64] f32

  const int t = threadIdx.x;
  const int w = t >> 6, lane = t & 63, quad = lane >> 4, l15 = lane & 15;
  const int h = w & 1, p = w >> 1;
  const int qt = blockIdx.x, b = blockIdx.y, sp = blockIdx.z;

  const unsigned short* Qg = Qb + (size_t)(b * 4096 + qt * 64 + h * 32) * 128;
  const unsigned short* Kg = Kb + (size_t)b * 4096 * 128;
  const unsigned short* Vg = Vt + (size_t)b * 128 * 4096;

  bf16x8 qf[2][4];
#pragma unroll
  for (int mt = 0; mt < 2; ++mt)
#pragma unroll
    for (int kk = 0; kk < 4; ++kk)
      qf[mt][kk] = *(const bf16x8*)&Qg[(size_t)(mt * 16 + l15) * 128 + kk * 32 + quad * 8];

  f32x4 O[2][8] = {};
  f32x4 Ol[2] = {};

  // staging maps (chunk-XOR swizzled on the fetch side):
  // K consumed as row = p*32 + 2*l15 + ntk with key l15&7 = (row>>1)&7, which
  // matches the staged key (t>>5)&7. V consumed with key l15&7 = row&7,
  // matching staged key (t>>3)&7.
  const unsigned short* kg0 = Kg + (size_t)(t >> 4) * 128 + (((t & 15) ^ ((t >> 5) & 7)) * 8);
  const unsigned short* vg0 = Vg + (size_t)(t >> 3) * 4096 + (((t & 7) ^ ((t >> 3) & 7)) * 8);

  const int kt0 = sp * 32;

  // prologue: stage K(0), V(0) into buffer 0
  {
    const unsigned short* kg = kg0 + (size_t)kt0 * 8192;
    const unsigned short* vg = vg0 + (size_t)kt0 * 64;
    unsigned short* kw = sm + w * 512;
    unsigned short* vw = sm + 16384 + w * 512;
#pragma unroll
    for (int it = 0; it < 4; ++it) load_lds16(kg + it * 2048, kw + it * 2048);
#pragma unroll
    for (int it = 0; it < 4; ++it) load_lds16(vg + (size_t)it * 131072, vw + it * 2048);
  }

  for (int i = 0; i < 32; ++i) {
    const int cur = i & 1, nxt = cur ^ 1;
    __syncthreads();   // ONLY barrier: drains 1-iter-old staging DMA (vmcnt(0))

    {  // stage tile i+1 into nxt (wrap dummy on last iter)
      const int ktn = (i < 31) ? (kt0 + i + 1) : kt0;
      const unsigned short* kg = kg0 + (size_t)ktn * 8192;
      const unsigned short* vg = vg0 + (size_t)ktn * 64;
      unsigned short* kw = sm + nxt * 8192 + w * 512;
      unsigned short* vw = sm + 16384 + nxt * 8192 + w * 512;
#pragma unroll
      for (int it = 0; it < 4; ++it) load_lds16(kg + it * 2048, kw + it * 2048);
#pragma unroll
      for (int it = 0; it < 4; ++it) load_lds16(vg + (size_t)it * 131072, vw + it * 2048);
    }

    // S = Q K^T on resident K buffer (keys paired even/odd: 2*l15+ntk)
    const unsigned short* Kc = sm + cur * 8192;
    f32x4 sc[2][2] = {};
#pragma unroll
    for (int ntk = 0; ntk < 2; ++ntk) {
      const int row = p * 32 + 2 * l15 + ntk;
#pragma unroll
      for (int kk = 0; kk < 4; ++kk) {
        bf16x8 kf = *(const bf16x8*)&Kc[row * 128 + (((kk * 4 + quad) ^ (l15 & 7)) * 8)];
        sc[0][ntk] = mfma16(qf[0][kk], kf, sc[0][ntk]);
        sc[1][ntk] = mfma16(qf[1][kk], kf, sc[1][ntk]);
      }
    }

    // P = exp(S) (no max shift), packed pair writes (keys 2*l15, 2*l15+1)
#pragma unroll
    for (int mt = 0; mt < 2; ++mt)
#pragma unroll
      for (int r = 0; r < 4; ++r) {
        float e0 = __expf(sc[mt][0][r]);
        float e1 = __expf(sc[mt][1][r]);
        int row = mt * 16 + quad * 4 + r;
        uint32_t pkv = (uint32_t)f2bf(e0) | ((uint32_t)f2bf(e1) << 16);
        *(uint32_t*)&Psh[w * 1280 + row * 40 + 2 * l15] = pkv;
      }
    asm volatile("s_waitcnt lgkmcnt(0)" ::: "memory");   // own P visible

    // O += P V on resident V buffer (staged a full iteration ago)
    const unsigned short* Vc = sm + 16384 + cur * 8192;
    bf16x8 pf0 = *(const bf16x8*)&Psh[w * 1280 + l15 * 40 + quad * 8];
    bf16x8 pf1 = *(const bf16x8*)&Psh[w * 1280 + (16 + l15) * 40 + quad * 8];
    const bf16x8 one = ones_bf16();
    Ol[0] = mfma16(pf0, one, Ol[0]);     // row-sums of P
    Ol[1] = mfma16(pf1, one, Ol[1]);
#pragma unroll
    for (int dt = 0; dt < 8; ++dt) {
      bf16x8 vf = *(const bf16x8*)&Vc[(dt * 16 + l15) * 64 + (((p * 4 + quad) ^ (l15 & 7)) * 8)];
      O[0][dt] = mfma16(pf0, vf, O[0][dt]);
      O[1][dt] = mfma16(pf1, vf, O[1][dt]);
    }
  }

  // ---- merge the two key-half partials (additive: no max state) ----
  __syncthreads();   // also drains the final dummy staging DMA before overlay
  if (p == 1) {
#pragma unroll
    for (int mt = 0; mt < 2; ++mt)
#pragma unroll
      for (int r = 0; r < 4; ++r) {
        int row = h * 32 + mt * 16 + quad * 4 + r;
        if (l15 == 0) lsh[row] = Ol[mt][r];
#pragma unroll
        for (int dt = 0; dt < 8; ++dt)
          Ob[row * 128 + dt * 16 + l15] = O[mt][dt][r];
      }
  }
  __syncthreads();
  if (p == 0) {
    const size_t rowbase = (size_t)b * 4096 + qt * 64;
    float* Omp = Om + (size_t)sp * 2097152;
#pragma unroll
    for (int mt = 0; mt < 2; ++mt)
#pragma unroll
      for (int r = 0; r < 4; ++r) {
        int row = h * 32 + mt * 16 + quad * 4 + r;
#pragma unroll
        for (int dt = 0; dt < 8; ++dt)
          Omp[(rowbase + row) * 128 + dt * 16 + l15] =
              O[mt][dt][r] + Ob[row * 128 + dt * 16 + l15];
        if (l15 == 0)
          lp[(size_t)sp * 16384 + rowbase + row] = Ol[mt][r] + lsh[row];
      }
  }
}

// ---------------------------------------------------------------- flash attention (fallback, static 59392 B)
// Round-4 structure: K dbuf + V single-buffer, mid-iter vmcnt(4)+barrier.
__global__ __launch_bounds__(256, 2) void k_flash_sb(
    const unsigned short* __restrict__ Qb,
    const unsigned short* __restrict__ Kb,
    const unsigned short* __restrict__ Vt,
    float* __restrict__ Om,
    float* __restrict__ lp)
{
  __shared__ __align__(16) unsigned short smem[8192 * 3 + 5120]; // 59392 B
  unsigned short* Vsh = smem + 16384;
  unsigned short* Psh = smem + 24576;
  float* Ob  = (float*)smem;
  float* lsh = (float*)(smem + 24576);

  const int t = threadIdx.x;
  const int w = t >> 6, lane = t & 63, quad = lane >> 4, l15 = lane & 15;
  const int h = w & 1, p = w >> 1;
  const int qt = blockIdx.x, b = blockIdx.y, sp = blockIdx.z;

  const unsigned short* Qg = Qb + (size_t)(b * 4096 + qt * 64 + h * 32) * 128;
  const unsigned short* Kg = Kb + (size_t)b * 4096 * 128;
  const unsigned short* Vg = Vt + (size_t)b * 128 * 4096;

  bf16x8 qf[2][4];
#pragma unroll
  for (int mt = 0; mt < 2; ++mt)
#pragma unroll
    for (int kk = 0; kk < 4; ++kk)
      qf[mt][kk] = *(const bf16x8*)&Qg[(size_t)(mt * 16 + l15) * 128 + kk * 32 + quad * 8];

  f32x4 O[2][8] = {};
  f32x4 Ol[2] = {};

  const unsigned short* kg0 = Kg + (size_t)(t >> 4) * 128 + (((t & 15) ^ ((t >> 5) & 7)) * 8);
  const unsigned short* vg0 = Vg + (size_t)(t >> 3) * 4096 + (((t & 7) ^ ((t >> 3) & 7)) * 8);
  unsigned short* vw = &Vsh[w * 512];

  const int kt0 = sp * 32;
  {
    const unsigned short* kg = kg0 + (size_t)kt0 * 8192;
    unsigned short* kw = &smem[w * 512];
#pragma unroll
    for (int it = 0; it < 4; ++it) load_lds16(kg + it * 2048, kw + it * 2048);
  }

  for (int i = 0; i < 32; ++i) {
    const int cur = i & 1, nxt = cur ^ 1;
    __syncthreads();
    {
      const unsigned short* vg = vg0 + (size_t)(kt0 + i) * 64;
#pragma unroll
      for (int it = 0; it < 4; ++it) load_lds16(vg + (size_t)it * 131072, vw + it * 2048);
      const int ktn = (i < 31) ? (kt0 + i + 1) : kt0;
      const unsigned short* kg = kg0 + (size_t)ktn * 8192;
      unsigned short* kw = &smem[nxt * 8192 + w * 512];
#pragma unroll
      for (int it = 0; it < 4; ++it) load_lds16(kg + it * 2048, kw + it * 2048);
    }

    const unsigned short* Kshc = &smem[cur * 8192];
    f32x4 sc[2][2] = {};
#pragma unroll
    for (int ntk = 0; ntk < 2; ++ntk) {
      const int row = p * 32 + 2 * l15 + ntk;
#pragma unroll
      for (int kk = 0; kk < 4; ++kk) {
        bf16x8 kf = *(const bf16x8*)&Kshc[row * 128 + (((kk * 4 + quad) ^ (l15 & 7)) * 8)];
        sc[0][ntk] = mfma16(qf[0][kk], kf, sc[0][ntk]);
        sc[1][ntk] = mfma16(qf[1][kk], kf, sc[1][ntk]);
      }
    }

#pragma unroll
    for (int mt = 0; mt < 2; ++mt)
#pragma unroll
      for (int r = 0; r < 4; ++r) {
        float e0 = __expf(sc[mt][0][r]);
        float e1 = __expf(sc[mt][1][r]);
        int row = mt * 16 + quad * 4 + r;
        uint32_t pkv = (uint32_t)f2bf(e0) | ((uint32_t)f2bf(e1) << 16);
        *(uint32_t*)&Psh[w * 1280 + row * 40 + 2 * l15] = pkv;
      }

    asm volatile("s_waitcnt vmcnt(4) lgkmcnt(0)" ::: "memory");
    asm volatile("s_barrier" ::: "memory");

    bf16x8 pf0 = *(const bf16x8*)&Psh[w * 1280 + l15 * 40 + quad * 8];
    bf16x8 pf1 = *(const bf16x8*)&Psh[w * 1280 + (16 + l15) * 40 + quad * 8];
    const bf16x8 one = ones_bf16();
    Ol[0] = mfma16(pf0, one, Ol[0]);
    Ol[1] = mfma16(pf1, one, Ol[1]);
#pragma unroll
    for (int dt = 0; dt < 8; ++dt) {
      bf16x8 vf = *(const bf16x8*)&Vsh[(dt * 16 + l15) * 64 + (((p * 4 + quad) ^ (l15 & 7)) * 8)];
      O[0][dt] = mfma16(pf0, vf, O[0][dt]);
      O[1][dt] = mfma16(pf1, vf, O[1][dt]);
    }
  }

  __syncthreads();
  if (p == 1) {
#pragma unroll
    for (int mt = 0; mt < 2; ++mt)
#pragma unroll
      for (int r = 0; r < 4; ++r) {
        int row = h * 32 + mt * 16 + quad * 4 + r;
        if (l15 == 0) lsh[row] = Ol[mt][r];
#pragma unroll
        for (int dt = 0; dt < 8; ++dt)
          Ob[row * 128 + dt * 16 + l15] = O[mt][dt][r];
      }
  }
  __syncthreads();
  if (p == 0) {
    const size_t rowbase = (size_t)b * 4096 + qt * 64;
    float* Omp = Om + (size_t)sp * 2097152;
#pragma unroll
    for (int mt = 0; mt < 2; ++mt)
#pragma unroll
      for (int r = 0; r < 4; ++r) {
        int row = h * 32 + mt * 16 + quad * 4 + r;
#pragma unroll
        for (int dt = 0; dt < 8; ++dt)
          Omp[(rowbase + row) * 128 + dt * 16 + l15] =
              O[mt][dt][r] + Ob[row * 128 + dt * 16 + l15];
        if (l15 == 0)
          lp[(size_t)sp * 16384 + rowbase + row] = Ol[mt][r] + lsh[row];
      }
  }
}

// ---------------------------------------------------------------- merge key-splits
__global__ __launch_bounds__(256) void k_merge(const float* __restrict__ Om,
                                               const float* __restrict__ lp,
                                               float* __restrict__ out) {
  int i = blockIdx.x * 256 + threadIdx.x;   // float4 index, 524288 total
  int row = i >> 5;
  float inv = 1.0f / (lp[row] + lp[16384 + row]);
  float4 a = ((const float4*)Om)[i];
  float4 c = ((const float4*)Om)[524288 + i];
  float4 o;
  o.x = (a.x + c.x) * inv;
  o.y = (a.y + c.y) * inv;
  o.z = (a.z + c.z) * inv;
  o.w = (a.w + c.w) * inv;
  ((float4*)out)[i] = o;
}

// ---------------------------------------------------------------- launch
extern "C" void kernel_launch(void* const* d_in, const int* in_sizes, int n_in,
                              void* d_out, int out_size, void* d_ws, size_t ws_size,
                              hipStream_t stream) {
  const float* x  = (const float*)d_in[0];   // [4,4096,1024]
  const float* Wq = (const float*)d_in[1];   // [128,1024]
  const float* Wk = (const float*)d_in[2];
  const float* Wv = (const float*)d_in[3];
  float* out = (float*)d_out;                // [4,4096,128]

  unsigned short* ws = (unsigned short*)d_ws;
  unsigned short* Qb = ws;                    // 2,097,152 ush
  unsigned short* Kb = ws + 2097152;
  unsigned short* Vt = ws + 4194304;
  float* lp = (float*)(ws + 6291456);         // 2*16384 f32
  float* Om = (float*)(ws + 6356992);         // 2*16384*128 f32

  k_proj<<<dim3(128, 3), 256, 0, stream>>>(x, Wq, Wk, Wv, Qb, Kb, Vt);

  const unsigned int DBU_LDS = 75776;
  hipError_t e = hipFuncSetAttribute(
      reinterpret_cast<const void*>(k_flash_db),
      hipFuncAttributeMaxDynamicSharedMemorySize, DBU_LDS);
  if (e == hipSuccess) {
    k_flash_db<<<dim3(64, 4, 2), 256, DBU_LDS, stream>>>(Qb, Kb, Vt, Om, lp);
  } else {
    k_flash_sb<<<dim3(64, 4, 2), 256, 0, stream>>>(Qb, Kb, Vt, Om, lp);
  }
  k_merge<<<2048, 256, 0, stream>>>(Om, lp, out);
}